// Round 1
// baseline (1262.876 us; speedup 1.0000x reference)
//
#include <hip/hip_runtime.h>
#include <hip/hip_fp16.h>

typedef _Float16 f16;
typedef _Float16 f16x2 __attribute__((ext_vector_type(2)));
typedef _Float16 f16x4v __attribute__((ext_vector_type(4)));
typedef _Float16 f16x8 __attribute__((ext_vector_type(8)));
typedef float f32x4 __attribute__((ext_vector_type(4)));

// Combined projection: rows 0..511 = Wq (8 heads x 64), 512..1023 = Wk,
// 1024..1055 = Ww (V), 1056..1311 = Wb (output). Padded to 1344 rows.
#define WC_ROWS 1312
#define WC_PAD 1344

// ---------------- prep: combined weight matrix (f16) + bias (f32) ----------------
__global__ void prep_weights(const float* __restrict__ Wq, const float* __restrict__ bq,
                             const float* __restrict__ Wk, const float* __restrict__ bk,
                             const float* __restrict__ Ww, const float* __restrict__ bw,
                             const float* __restrict__ Wb, const float* __restrict__ bb,
                             f16* __restrict__ Wc, float* __restrict__ bias) {
    int id = blockIdx.x * 256 + threadIdx.x;   // WC_PAD*256 threads
    int j = id >> 8, k = id & 255;
    if (j >= WC_PAD) return;
    float v;
    if (j < 512)       v = Wq[j*256 + k];          // Wq flat [8,64,256]: row h*64+d == j
    else if (j < 1024) v = Wk[(j-512)*256 + k];
    else if (j < 1056) v = Ww[(j-1024)*256 + k];
    else if (j < 1312) v = Wb[(j-1056)*256 + k];
    else               v = 0.f;
    Wc[j*256 + k] = (f16)v;
    if (k == 0) {
        float b;
        if (j < 512)       b = bq[j];
        else if (j < 1024) b = bk[j-512];
        else if (j < 1056) b = bw[j-1024];
        else if (j < 1312) b = bb[j-1056];
        else               b = 0.f;
        bias[j] = b;
    }
}

// ---------------- prep: features fp32 -> f16, zero-pad rows >= n ----------------
__global__ void conv_feat(const float* __restrict__ F, f16* __restrict__ Fh,
                          int n, long total) {
    long id = (long)blockIdx.x * 256 + threadIdx.x;
    long base = id * 4;
    if (base >= total) return;
    long row = base >> 8;
    float4 v = make_float4(0.f, 0.f, 0.f, 0.f);
    if (row < n) v = *(const float4*)(F + base);
    f16x4v o = { (f16)v.x, (f16)v.y, (f16)v.z, (f16)v.w };
    *(f16x4v*)(Fh + base) = o;
}

// ---------------- prep: CSR row starts (edges sorted by src; every row non-empty) --
__global__ void build_rows(const int* __restrict__ src, int E, int n, int* __restrict__ rs) {
    int e = blockIdx.x * 256 + threadIdx.x;
    if (e == 0) rs[n] = E;
    if (e < E) {
        if (e == 0 || src[e] != src[e-1]) rs[src[e]] = e;
    }
}

// ---------------- fused projection GEMM ----------------
// C[m][g] = sum_k Fh[m][k] * Wc[g][k] + bias[g];  scatter by g-region.
// Tile 128x64, BK=32, 4 waves (2x2), mfma_f32_16x16x32_f16.
__device__ __forceinline__ int swz_slot(int row, int c) {
    // 16B-slot swizzle: 2-way (free) LDS bank pattern for stride-64B b128 frag reads
    return row * 4 + (c ^ (row & 3) ^ ((row >> 2) & 3));
}

__launch_bounds__(256)
__global__ void gemm_fused(const f16* __restrict__ A, const f16* __restrict__ Wc,
                           const float* __restrict__ bias,
                           f16* __restrict__ Qb, f16* __restrict__ Kb, f16* __restrict__ Vb,
                           float* __restrict__ Out, int n) {
    __shared__ uint4 As4[512];   // 128 rows x 32 k (f16) = 8KB
    __shared__ uint4 Bs4[256];   // 64 rows x 32 k = 4KB
    int t = threadIdx.x;
    int lane = t & 63, w = t >> 6;
    int wm = w >> 1, wn = w & 1;
    long m0 = (long)blockIdx.x * 128;
    int n0 = blockIdx.y * 64;

    f32x4 acc[4][2];
    #pragma unroll
    for (int i = 0; i < 4; i++)
        #pragma unroll
        for (int j = 0; j < 2; j++)
            acc[i][j] = (f32x4){0.f, 0.f, 0.f, 0.f};

    int lrow = t >> 2, lc = t & 3;
    const uint4* Ag0 = (const uint4*)(A + (m0 + lrow) * 256 + lc * 8);
    const uint4* Ag1 = (const uint4*)(A + (m0 + 64 + lrow) * 256 + lc * 8);
    const uint4* Bg  = (const uint4*)(Wc + (long)(n0 + lrow) * 256 + lc * 8);
    int ws0 = swz_slot(lrow, lc);
    int ws1 = swz_slot(lrow + 64, lc);
    int csw = (lane >> 4) ^ (lane & 3) ^ ((lane >> 2) & 3);
    int arow = wm * 64 + (lane & 15);
    int brow = wn * 32 + (lane & 15);

    uint4 ra0 = Ag0[0], ra1 = Ag1[0], rb = Bg[0];
    for (int kt = 0; kt < 8; ++kt) {
        if (kt) __syncthreads();
        As4[ws0] = ra0;
        As4[ws1] = ra1;
        Bs4[ws0] = rb;
        __syncthreads();
        if (kt < 7) {            // prefetch next K-slice (row stride 32 uint4, k step 4)
            ra0 = Ag0[(kt + 1) * 4];
            ra1 = Ag1[(kt + 1) * 4];
            rb  = Bg[(kt + 1) * 4];
        }
        f16x8 af[4], bf[2];
        const f16x8* Ap = (const f16x8*)As4;
        const f16x8* Bp = (const f16x8*)Bs4;
        #pragma unroll
        for (int i = 0; i < 4; i++) af[i] = Ap[(arow + i * 16) * 4 + csw];
        #pragma unroll
        for (int j = 0; j < 2; j++) bf[j] = Bp[(brow + j * 16) * 4 + csw];
        #pragma unroll
        for (int i = 0; i < 4; i++)
            #pragma unroll
            for (int j = 0; j < 2; j++)
                acc[i][j] = __builtin_amdgcn_mfma_f32_16x16x32_f16(af[i], bf[j], acc[i][j], 0, 0, 0);
    }

    // epilogue: C row = (lane>>4)*4 + reg, col = lane&15  [guide §3, m89-verified]
    #pragma unroll
    for (int i = 0; i < 4; i++) {
        long gmb = m0 + wm * 64 + i * 16 + (lane >> 4) * 4;
        #pragma unroll
        for (int j = 0; j < 2; j++) {
            int gn = n0 + wn * 32 + j * 16 + (lane & 15);
            float bv = bias[gn];
            #pragma unroll
            for (int r = 0; r < 4; r++) {
                long gm = gmb + r;
                if (gm >= n) continue;
                float v = acc[i][j][r] + bv;
                if (gn < 512)       Qb[gm * 512 + gn] = (f16)v;
                else if (gn < 1024) Kb[gm * 512 + (gn - 512)] = (f16)v;
                else if (gn < 1056) Vb[gm * 32 + (gn - 1024)] = (f16)v;
                else if (gn < 1312) Out[gm * 256 + (gn - 1056)] = v;
            }
        }
    }
}

// ---------------- edge attention: one wave per row, flash-style ----------------
__device__ __forceinline__ float fd2(unsigned a, unsigned b, float c) {
#if defined(__has_builtin)
#if __has_builtin(__builtin_amdgcn_fdot2)
    return __builtin_amdgcn_fdot2(__builtin_bit_cast(f16x2, a), __builtin_bit_cast(f16x2, b), c, false);
#else
    f16x2 x = __builtin_bit_cast(f16x2, a), y = __builtin_bit_cast(f16x2, b);
    return c + (float)x[0] * (float)y[0] + (float)x[1] * (float)y[1];
#endif
#else
    f16x2 x = __builtin_bit_cast(f16x2, a), y = __builtin_bit_cast(f16x2, b);
    return c + (float)x[0] * (float)y[0] + (float)x[1] * (float)y[1];
#endif
}

__launch_bounds__(256)
__global__ void edge_attn(const int* __restrict__ rs, const int* __restrict__ dstA,
                          const f16* __restrict__ Qb, const f16* __restrict__ Kb,
                          const f16* __restrict__ Vb, float* __restrict__ Out, int n) {
    __shared__ float pS[4][64][8];   // unnormalized exp scores
    __shared__ int   dS[4][64];      // dst per edge slot
    int w = threadIdx.x >> 6, lane = threadIdx.x & 63;
    int row = blockIdx.x * 4 + w;
    if (row >= n) return;
    int e0 = rs[row], e1 = rs[row + 1];
    int deg = e1 - e0;
    const uint4* qp = (const uint4*)(Qb + (size_t)row * 512);
    float m[8], l[8];
    #pragma unroll
    for (int h = 0; h < 8; h++) { m[h] = -1e30f; l[h] = 0.f; }
    float acc[4] = {0.f, 0.f, 0.f, 0.f};
    int h0 = lane >> 5;   // lane covers out dims lane+64k -> heads h0+2k

    for (int base = 0; base < deg; base += 64) {
        int nE = min(64, deg - base);
        bool act = lane < nE;
        int d = dstA[e0 + base + (act ? lane : nE - 1)];
        dS[w][lane] = d;
        const uint4* kp = (const uint4*)(Kb + (size_t)d * 512);
        // 8-head scores: 512-dim f16 dot via v_dot2
        float s[8];
        #pragma unroll
        for (int h = 0; h < 8; h++) {
            float a = 0.f;
            #pragma unroll
            for (int c = 0; c < 8; c++) {
                uint4 kv = kp[h * 8 + c], qv = qp[h * 8 + c];
                a = fd2(qv.x, kv.x, a);
                a = fd2(qv.y, kv.y, a);
                a = fd2(qv.z, kv.z, a);
                a = fd2(qv.w, kv.w, a);
            }
            s[h] = a;
        }
        // online softmax (butterfly reduce across the wave)
        float sc[8];
        #pragma unroll
        for (int h = 0; h < 8; h++) {
            float sv = act ? s[h] : -1e30f;
            #pragma unroll
            for (int off = 1; off < 64; off <<= 1) sv = fmaxf(sv, __shfl_xor(sv, off));
            float nm = fmaxf(m[h], sv);
            sc[h] = __expf(m[h] - nm);
            float p = act ? __expf(s[h] - nm) : 0.f;
            pS[w][lane][h] = p;
            #pragma unroll
            for (int off = 1; off < 64; off <<= 1) p += __shfl_xor(p, off);
            l[h] = l[h] * sc[h] + p;
            m[h] = nm;
        }
        #pragma unroll
        for (int k = 0; k < 4; k++) {          // static-index select (rule #20)
            float f = h0 ? sc[2*k + 1] : sc[2*k];
            acc[k] *= f;
        }
        // aggregation: lane = output dim; V broadcast per edge
        for (int e = 0; e < nE; ++e) {
            int d2 = dS[w][e];
            float v = (float)Vb[(size_t)d2 * 32 + (lane & 31)];
            #pragma unroll
            for (int k = 0; k < 4; k++) acc[k] += pS[w][e][h0 + 2*k] * v;
        }
    }
    float* op = Out + (size_t)row * 256;
    #pragma unroll
    for (int k = 0; k < 4; k++) {
        float dn = h0 ? l[2*k + 1] : l[2*k];
        op[lane + 64 * k] += acc[k] / dn;
    }
}

// ---------------- launch ----------------
extern "C" void kernel_launch(void* const* d_in, const int* in_sizes, int n_in,
                              void* d_out, int out_size, void* d_ws, size_t ws_size,
                              hipStream_t stream) {
    const float* F  = (const float*)d_in[0];
    const int*   ei = (const int*)d_in[1];
    const float* Wq = (const float*)d_in[2];
    const float* bq = (const float*)d_in[3];
    const float* Wk = (const float*)d_in[4];
    const float* bk = (const float*)d_in[5];
    const float* Ww = (const float*)d_in[6];
    const float* bw = (const float*)d_in[7];
    const float* Wb = (const float*)d_in[8];
    const float* bb = (const float*)d_in[9];
    int n = in_sizes[0] / 256;       // 50000
    int E = in_sizes[1] / 2;
    const int* srcA = ei;
    const int* dstA = ei + E;
    int n_pad = (n + 127) & ~127;

    // workspace carve-out (~132 MB)
    char* wp = (char*)d_ws;
    auto alloc = [&](size_t bytes) { void* p = wp; wp += (bytes + 255) & ~255ull; return p; };
    f16*   Fh   = (f16*)alloc((size_t)n_pad * 256 * 2);
    f16*   Wc   = (f16*)alloc((size_t)WC_PAD * 256 * 2);
    float* bias = (float*)alloc((size_t)WC_PAD * 4);
    f16*   Qb   = (f16*)alloc((size_t)n * 512 * 2);
    f16*   Kb   = (f16*)alloc((size_t)n * 512 * 2);
    f16*   Vb   = (f16*)alloc((size_t)n * 32 * 2);
    int*   rs   = (int*)alloc((size_t)(n + 1) * 4);
    float* Out  = (float*)d_out;

    prep_weights<<<WC_PAD, 256, 0, stream>>>(Wq, bq, Wk, bk, Ww, bw, Wb, bb, Wc, bias);
    long totalF = (long)n_pad * 256;
    conv_feat<<<(int)((totalF / 4 + 255) / 256), 256, 0, stream>>>(F, Fh, n, totalF);
    build_rows<<<(E + 255) / 256, 256, 0, stream>>>(srcA, E, n, rs);
    dim3 g(n_pad / 128, WC_PAD / 64);
    gemm_fused<<<g, 256, 0, stream>>>(Fh, Wc, bias, Qb, Kb, Vb, Out, n);
    edge_attn<<<(n + 3) / 4, 256, 0, stream>>>(rs, dstA, Qb, Kb, Vb, Out, n);
}